// Round 2
// baseline (584.086 us; speedup 1.0000x reference)
//
#include <hip/hip_runtime.h>
#include <hip/hip_bf16.h>

#define DM 768
#define NH 12
#define DK 64
#define SEQ 2048
#define NB 2
#define M_ (NB*SEQ)   // 4096

typedef __bf16 bf16;
typedef bf16 bf16x8 __attribute__((ext_vector_type(8)));
typedef float f32x4 __attribute__((ext_vector_type(4)));
typedef float f32x8 __attribute__((ext_vector_type(8)));

__device__ __forceinline__ f32x4 mfma16(bf16x8 a, bf16x8 b, f32x4 c) {
    return __builtin_amdgcn_mfma_f32_16x16x32_bf16(a, b, c, 0, 0, 0);
}

__device__ __forceinline__ bf16x8 cvt8(const float* __restrict__ p) {
    f32x8 v = *(const f32x8*)p;
    bf16x8 r;
#pragma unroll
    for (int j = 0; j < 8; ++j) r[j] = (bf16)v[j];
    return r;
}

// ---------------- QKV projection: C = X @ W^T + b (f32 in, bf16 out to ws) ----------------
// grid: (M/64, DM/64, 3); block 256 (4 waves); wave w does rows m0+16w, 64 cols.
__global__ __launch_bounds__(256) void qkv_proj_kernel(
    const float* __restrict__ qx, const float* __restrict__ kx, const float* __restrict__ vx,
    const float* __restrict__ wq, const float* __restrict__ wk, const float* __restrict__ wv,
    const float* __restrict__ bq, const float* __restrict__ bk, const float* __restrict__ bv,
    bf16* __restrict__ Qh, bf16* __restrict__ Kh, bf16* __restrict__ Vt)
{
    int z = blockIdx.z;
    const float* X  = (z == 0) ? qx : (z == 1) ? kx : vx;
    const float* W  = (z == 0) ? wq : (z == 1) ? wk : wv;
    const float* Bi = (z == 0) ? bq : (z == 1) ? bk : bv;

    int lane = threadIdx.x & 63;
    int w = threadIdx.x >> 6;
    int g = lane >> 4, c = lane & 15;
    int m0 = blockIdx.x * 64 + w * 16;
    int n0 = blockIdx.y * 64;

    f32x4 acc[4] = {};
    const float* xrow  = X + (size_t)(m0 + c) * DM + g * 8;
    const float* wbase = W + (size_t)(n0 + c) * DM + g * 8;
    for (int kk = 0; kk < DM; kk += 32) {
        bf16x8 a = cvt8(xrow + kk);
#pragma unroll
        for (int t = 0; t < 4; ++t) {
            bf16x8 b = cvt8(wbase + (size_t)t * 16 * DM + kk);
            acc[t] = mfma16(a, b, acc[t]);
        }
    }
#pragma unroll
    for (int t = 0; t < 4; ++t) {
        int n = n0 + t * 16 + c;
        float bias = Bi[n];
        int h = n >> 6, dk = n & 63;
#pragma unroll
        for (int r = 0; r < 4; ++r) {
            int m = m0 + g * 4 + r;
            int b_ = m >> 11, s = m & (SEQ - 1);
            float val = acc[t][r] + bias;
            if (z == 2) {
                Vt[((size_t)(b_ * NH + h) * DK + dk) * SEQ + s] = (bf16)val;
            } else {
                bf16* dst = (z == 0) ? Qh : Kh;
                dst[((size_t)(b_ * NH + h) * SEQ + s) * DK + dk] = (bf16)val;
            }
        }
    }
}

// ---------------- Flash attention, causal. S^T = K@Q^T trick, no LDS. ----------------
// grid: (SEQ/64, NB*NH); block 256. Wave w handles q rows [q0, q0+16).
__global__ __launch_bounds__(256) void attn_kernel(
    const bf16* __restrict__ Qh, const bf16* __restrict__ Kh, const bf16* __restrict__ Vt,
    bf16* __restrict__ Xo)
{
    int bh = blockIdx.y;
    int lane = threadIdx.x & 63, w = threadIdx.x >> 6;
    int g = lane >> 4, c = lane & 15;
    const bf16* Qb = Qh + (size_t)bh * SEQ * DK;
    const bf16* Kb = Kh + (size_t)bh * SEQ * DK;
    const bf16* Vb = Vt + (size_t)bh * DK * SEQ;
    int q0 = blockIdx.x * 64 + w * 16;

    // Q as MFMA B-operand: B[k=dk][n=q_local]; lane reads Q[q0+c][dk=8g..8g+7]
    bf16x8 qf0 = *(const bf16x8*)(Qb + (size_t)(q0 + c) * DK + g * 8);
    bf16x8 qf1 = *(const bf16x8*)(Qb + (size_t)(q0 + c) * DK + 32 + g * 8);

    float m_st = -INFINITY, l_st = 0.f;
    f32x4 o[4] = {};
    int myq = q0 + c;
    int srcA = g * 20;  // lane g*16 + (4g) : holds state for q_local = 4g+r at +r

    int kend = q0 + 16;  // keys needed: <= q0+15
    for (int kb = 0; kb < kend; kb += 32) {
        // K as A-operand: A[m=key_local=c][k=dk]
        bf16x8 k00 = *(const bf16x8*)(Kb + (size_t)(kb + c) * DK + g * 8);
        bf16x8 k01 = *(const bf16x8*)(Kb + (size_t)(kb + c) * DK + 32 + g * 8);
        bf16x8 k10 = *(const bf16x8*)(Kb + (size_t)(kb + 16 + c) * DK + g * 8);
        bf16x8 k11 = *(const bf16x8*)(Kb + (size_t)(kb + 16 + c) * DK + 32 + g * 8);
        f32x4 st0 = {}, st1 = {};
        st0 = mfma16(k00, qf0, st0); st0 = mfma16(k01, qf1, st0);
        st1 = mfma16(k10, qf0, st1); st1 = mfma16(k11, qf1, st1);
        // S^T C-layout: reg r at lane (g,c) = S[q=q0+c][key=kb+4g+r] (st0), +16 (st1)
        float s0[4], s1[4];
        float mx = -INFINITY;
#pragma unroll
        for (int r = 0; r < 4; ++r) {
            int key0 = kb + g * 4 + r;
            s0[r] = (key0 <= myq) ? st0[r] * 0.125f : -INFINITY;
            s1[r] = (key0 + 16 <= myq) ? st1[r] * 0.125f : -INFINITY;
            mx = fmaxf(mx, fmaxf(s0[r], s1[r]));
        }
        mx = fmaxf(mx, __shfl_xor(mx, 16, 64));
        mx = fmaxf(mx, __shfl_xor(mx, 32, 64));
        float m_new = fmaxf(m_st, mx);
        float alpha = __expf(m_st - m_new);
        m_st = m_new;
        float psum = 0.f;
#pragma unroll
        for (int r = 0; r < 4; ++r) {
            s0[r] = __expf(s0[r] - m_new);
            s1[r] = __expf(s1[r] - m_new);
            psum += s0[r] + s1[r];
        }
        psum += __shfl_xor(psum, 16, 64);
        psum += __shfl_xor(psum, 32, 64);
        l_st = l_st * alpha + psum;
        // rescale O by alpha of its rows (q_local = 4g+r)
        float ar[4];
#pragma unroll
        for (int r = 0; r < 4; ++r) ar[r] = __shfl(alpha, srcA + r, 64);
#pragma unroll
        for (int t = 0; t < 4; ++t)
#pragma unroll
            for (int r = 0; r < 4; ++r) o[t][r] *= ar[r];
        // relayout P (S^T C-layout) -> A-operand layout: lane (g,c) needs P[q=c][key=8g+j]
        bf16x8 pa;
        int use_hi = g >> 1;
        int gsb = (g & 1) * 2;
#pragma unroll
        for (int j = 0; j < 8; ++j) {
            int r = j & 3;
            int srcLane = (gsb + (j >> 2)) * 16 + c;
            float v0 = __shfl(s0[r], srcLane, 64);
            float v1 = __shfl(s1[r], srcLane, 64);
            pa[j] = (bf16)(use_hi ? v1 : v0);
        }
        // PV: B[k=key][n=dv] from Vt (transposed): lane reads Vt[dv=t*16+c][kb+8g..+8]
#pragma unroll
        for (int t = 0; t < 4; ++t) {
            bf16x8 bv = *(const bf16x8*)(Vb + (size_t)(t * 16 + c) * SEQ + kb + g * 8);
            o[t] = mfma16(pa, bv, o[t]);
        }
    }
    float inv = 1.f / l_st;
    float ir[4];
#pragma unroll
    for (int r = 0; r < 4; ++r) ir[r] = __shfl(inv, srcA + r, 64);
    int b_ = bh / NH, h = bh % NH;
#pragma unroll
    for (int t = 0; t < 4; ++t) {
#pragma unroll
        for (int r = 0; r < 4; ++r) {
            int s = q0 + g * 4 + r;
            Xo[(size_t)(b_ * SEQ + s) * DM + h * DK + t * 16 + c] = (bf16)(o[t][r] * ir[r]);
        }
    }
}

// ---------------- Output projection: out = X @ wo^T + bo (bf16 X, f32 W, f32 out) ----------------
__global__ __launch_bounds__(256) void oproj_kernel(
    const bf16* __restrict__ X, const float* __restrict__ W, const float* __restrict__ Bi,
    float* __restrict__ out)
{
    int lane = threadIdx.x & 63;
    int w = threadIdx.x >> 6;
    int g = lane >> 4, c = lane & 15;
    int m0 = blockIdx.x * 64 + w * 16;
    int n0 = blockIdx.y * 64;

    f32x4 acc[4] = {};
    const bf16* xrow   = X + (size_t)(m0 + c) * DM + g * 8;
    const float* wbase = W + (size_t)(n0 + c) * DM + g * 8;
    for (int kk = 0; kk < DM; kk += 32) {
        bf16x8 a = *(const bf16x8*)(xrow + kk);
#pragma unroll
        for (int t = 0; t < 4; ++t) {
            bf16x8 b = cvt8(wbase + (size_t)t * 16 * DM + kk);
            acc[t] = mfma16(a, b, acc[t]);
        }
    }
#pragma unroll
    for (int t = 0; t < 4; ++t) {
        int n = n0 + t * 16 + c;
        float bias = Bi[n];
#pragma unroll
        for (int r = 0; r < 4; ++r) {
            int m = m0 + g * 4 + r;
            out[(size_t)m * DM + n] = acc[t][r] + bias;
        }
    }
}

extern "C" void kernel_launch(void* const* d_in, const int* in_sizes, int n_in,
                              void* d_out, int out_size, void* d_ws, size_t ws_size,
                              hipStream_t stream) {
    const float* q  = (const float*)d_in[0];
    const float* k  = (const float*)d_in[1];
    const float* v  = (const float*)d_in[2];
    // d_in[3] = causal tril mask (int32) — statically known, unused
    const float* wq = (const float*)d_in[4];
    const float* bq = (const float*)d_in[5];
    const float* wk = (const float*)d_in[6];
    const float* bk = (const float*)d_in[7];
    const float* wv = (const float*)d_in[8];
    const float* bv = (const float*)d_in[9];
    const float* wo = (const float*)d_in[10];
    const float* bo = (const float*)d_in[11];

    const size_t headsz = (size_t)NB * NH * SEQ * DK;  // 3.1M elems
    bf16* Qh = (bf16*)d_ws;
    bf16* Kh = Qh + headsz;
    bf16* Vt = Kh + headsz;
    bf16* Xo = Vt + headsz;
    float* out = (float*)d_out;

    dim3 blk(256);
    qkv_proj_kernel<<<dim3(M_ / 64, DM / 64, 3), blk, 0, stream>>>(
        q, k, v, wq, wk, wv, bq, bk, bv, Qh, Kh, Vt);
    attn_kernel<<<dim3(SEQ / 64, NB * NH), blk, 0, stream>>>(Qh, Kh, Vt, Xo);
    oproj_kernel<<<dim3(M_ / 64, DM / 64), blk, 0, stream>>>(Xo, wo, bo, out);
}

// Round 3
// 322.508 us; speedup vs baseline: 1.8111x; 1.8111x over previous
//
#include <hip/hip_runtime.h>
#include <hip/hip_bf16.h>

#define DM 768
#define NH 12
#define DK 64
#define SEQ 2048
#define NB 2
#define M_ (NB*SEQ)   // 4096
#define XN 3145728    // M_*DM
#define WN 589824     // DM*DM

typedef __bf16 bf16;
typedef bf16 bf16x4 __attribute__((ext_vector_type(4)));
typedef bf16 bf16x8 __attribute__((ext_vector_type(8)));
typedef float f32x4 __attribute__((ext_vector_type(4)));

__device__ __forceinline__ f32x4 mfma16(bf16x8 a, bf16x8 b, f32x4 c) {
    return __builtin_amdgcn_mfma_f32_16x16x32_bf16(a, b, c, 0, 0, 0);
}

__device__ __forceinline__ void gload_lds16(const bf16* g, bf16* l) {
    __builtin_amdgcn_global_load_lds(
        (const __attribute__((address_space(1))) void*)g,
        (__attribute__((address_space(3))) void*)l, 16, 0, 0);
}

// ---------------- f32 -> bf16 convert (X: q,k,v ; W: wq,wk,wv,wo) ----------------
__global__ __launch_bounds__(256) void convert_kernel(
    const float* __restrict__ q, const float* __restrict__ k, const float* __restrict__ v,
    const float* __restrict__ wq, const float* __restrict__ wk, const float* __restrict__ wv,
    const float* __restrict__ wo, bf16* __restrict__ Xb, bf16* __restrict__ Wb)
{
    long long e = ((long long)blockIdx.x * 256 + threadIdx.x) * 8;
    const float* src; bf16* dst;
    if (e < 3LL * XN) {
        int z = (int)(e / XN);
        src = (z == 0 ? q : z == 1 ? k : v) + (e - (long long)z * XN);
        dst = Xb + e;
    } else {
        long long e2 = e - 3LL * XN;
        int z = (int)(e2 / WN);
        src = (z == 0 ? wq : z == 1 ? wk : z == 2 ? wv : wo) + (e2 - (long long)z * WN);
        dst = Wb + e2;
    }
    f32x4 a = *(const f32x4*)src;
    f32x4 b = *(const f32x4*)(src + 4);
    bf16x8 o;
#pragma unroll
    for (int j = 0; j < 4; ++j) { o[j] = (bf16)a[j]; o[j + 4] = (bf16)b[j]; }
    *(bf16x8*)dst = o;
}

// ---------------- QKV GEMM: BM=128 BN=64 BK=64, LDS-staged via global_load_lds ----------------
// LDS layout: A [kk2][128 m][32 k] at 0..8191 elems; B [kk2][64 n][32 k] at 8192..12287.
// grid (32, 12, 3), block 256 (4 waves, 2x2, each 64x32 = 4x2 frags).
__global__ __launch_bounds__(256) void qkv_gemm_kernel(
    const bf16* __restrict__ Xb, const bf16* __restrict__ Wb,
    const float* __restrict__ bq, const float* __restrict__ bk, const float* __restrict__ bv,
    bf16* __restrict__ Qh, bf16* __restrict__ Kh, bf16* __restrict__ Vt)
{
    __shared__ bf16 lds[12288];
    int z = blockIdx.z;
    const bf16* Ab = Xb + (size_t)z * XN;
    const bf16* Wz = Wb + (size_t)z * WN;
    const float* Bi = (z == 0) ? bq : (z == 1) ? bk : bv;

    int t = threadIdx.x;
    int lane = t & 63, w = t >> 6;
    int g = lane >> 4, c = lane & 15;
    int wm = (w >> 1) * 64, wn = (w & 1) * 32;
    int m0 = blockIdx.x * 128, n0 = blockIdx.y * 64;

    f32x4 acc[4][2] = {};

    const bf16* Agp[4];
#pragma unroll
    for (int r = 0; r < 4; ++r) {
        int e = r * 2048 + t * 8;
        int kk = e >> 12, mm = (e & 4095) >> 5, k8 = e & 31;
        Agp[r] = Ab + (size_t)(m0 + mm) * DM + kk * 32 + k8;
    }
    const bf16* Bgp[2];
#pragma unroll
    for (int r = 0; r < 2; ++r) {
        int e = r * 2048 + t * 8;
        int kk = e >> 11, nn = (e & 2047) >> 5, k8 = e & 31;
        Bgp[r] = Wz + (size_t)(n0 + nn) * DM + kk * 32 + k8;
    }

    for (int kt = 0; kt < 12; ++kt) {
#pragma unroll
        for (int r = 0; r < 4; ++r)
            gload_lds16(Agp[r] + kt * 64, &lds[r * 2048 + t * 8]);
#pragma unroll
        for (int r = 0; r < 2; ++r)
            gload_lds16(Bgp[r] + kt * 64, &lds[8192 + r * 2048 + t * 8]);
        __syncthreads();
        bf16x8 af[4][2], bfr[2][2];
#pragma unroll
        for (int kk = 0; kk < 2; ++kk) {
#pragma unroll
            for (int mi = 0; mi < 4; ++mi)
                af[mi][kk] = *(const bf16x8*)&lds[kk * 4096 + (wm + mi * 16 + c) * 32 + g * 8];
#pragma unroll
            for (int ni = 0; ni < 2; ++ni)
                bfr[ni][kk] = *(const bf16x8*)&lds[8192 + kk * 2048 + (wn + ni * 16 + c) * 32 + g * 8];
        }
#pragma unroll
        for (int mi = 0; mi < 4; ++mi)
#pragma unroll
            for (int ni = 0; ni < 2; ++ni) {
                acc[mi][ni] = mfma16(af[mi][0], bfr[ni][0], acc[mi][ni]);
                acc[mi][ni] = mfma16(af[mi][1], bfr[ni][1], acc[mi][ni]);
            }
        __syncthreads();
    }

    int b_ = m0 >> 11, sbase = m0 & (SEQ - 1);
    int h = blockIdx.y;
    if (z < 2) {
        bf16* dst = (z == 0) ? Qh : Kh;
#pragma unroll
        for (int ni = 0; ni < 2; ++ni) {
            int nl = wn + ni * 16 + c;   // dk
            float bias = Bi[n0 + nl];
#pragma unroll
            for (int mi = 0; mi < 4; ++mi)
#pragma unroll
                for (int r = 0; r < 4; ++r) {
                    int s = sbase + wm + mi * 16 + g * 4 + r;
                    dst[((size_t)(b_ * NH + h) * SEQ + s) * DK + nl] = (bf16)(acc[mi][ni][r] + bias);
                }
        }
    } else {
        // V: transpose 128(s) x 64(dk) tile through LDS -> Vt[bh][dk][s], coalesced stores
#pragma unroll
        for (int ni = 0; ni < 2; ++ni) {
            int nl = wn + ni * 16 + c;
            float bias = Bi[n0 + nl];
#pragma unroll
            for (int mi = 0; mi < 4; ++mi) {
                bf16x4 pk;
#pragma unroll
                for (int r = 0; r < 4; ++r) pk[r] = (bf16)(acc[mi][ni][r] + bias);
                *(bf16x4*)&lds[nl * 136 + wm + mi * 16 + g * 4] = pk;
            }
        }
        __syncthreads();
        int dk = t >> 2, sc = (t & 3) * 32;
        bf16* vdst = Vt + ((size_t)(b_ * NH + h) * DK + dk) * SEQ + sbase + sc;
#pragma unroll
        for (int j = 0; j < 4; ++j)
            *(bf16x8*)(vdst + j * 8) = *(const bf16x8*)&lds[dk * 136 + sc + j * 8];
    }
}

// ---------------- Output projection GEMM: same structure, f32 output ----------------
__global__ __launch_bounds__(256) void o_gemm_kernel(
    const bf16* __restrict__ Xo, const bf16* __restrict__ Wo,
    const float* __restrict__ bo, float* __restrict__ out)
{
    __shared__ bf16 lds[12288];
    int t = threadIdx.x;
    int lane = t & 63, w = t >> 6;
    int g = lane >> 4, c = lane & 15;
    int wm = (w >> 1) * 64, wn = (w & 1) * 32;
    int m0 = blockIdx.x * 128, n0 = blockIdx.y * 64;

    f32x4 acc[4][2] = {};

    const bf16* Agp[4];
#pragma unroll
    for (int r = 0; r < 4; ++r) {
        int e = r * 2048 + t * 8;
        int kk = e >> 12, mm = (e & 4095) >> 5, k8 = e & 31;
        Agp[r] = Xo + (size_t)(m0 + mm) * DM + kk * 32 + k8;
    }
    const bf16* Bgp[2];
#pragma unroll
    for (int r = 0; r < 2; ++r) {
        int e = r * 2048 + t * 8;
        int kk = e >> 11, nn = (e & 2047) >> 5, k8 = e & 31;
        Bgp[r] = Wo + (size_t)(n0 + nn) * DM + kk * 32 + k8;
    }

    for (int kt = 0; kt < 12; ++kt) {
#pragma unroll
        for (int r = 0; r < 4; ++r)
            gload_lds16(Agp[r] + kt * 64, &lds[r * 2048 + t * 8]);
#pragma unroll
        for (int r = 0; r < 2; ++r)
            gload_lds16(Bgp[r] + kt * 64, &lds[8192 + r * 2048 + t * 8]);
        __syncthreads();
        bf16x8 af[4][2], bfr[2][2];
#pragma unroll
        for (int kk = 0; kk < 2; ++kk) {
#pragma unroll
            for (int mi = 0; mi < 4; ++mi)
                af[mi][kk] = *(const bf16x8*)&lds[kk * 4096 + (wm + mi * 16 + c) * 32 + g * 8];
#pragma unroll
            for (int ni = 0; ni < 2; ++ni)
                bfr[ni][kk] = *(const bf16x8*)&lds[8192 + kk * 2048 + (wn + ni * 16 + c) * 32 + g * 8];
        }
#pragma unroll
        for (int mi = 0; mi < 4; ++mi)
#pragma unroll
            for (int ni = 0; ni < 2; ++ni) {
                acc[mi][ni] = mfma16(af[mi][0], bfr[ni][0], acc[mi][ni]);
                acc[mi][ni] = mfma16(af[mi][1], bfr[ni][1], acc[mi][ni]);
            }
        __syncthreads();
    }

#pragma unroll
    for (int ni = 0; ni < 2; ++ni) {
        int n = n0 + wn + ni * 16 + c;
        float bias = bo[n];
#pragma unroll
        for (int mi = 0; mi < 4; ++mi)
#pragma unroll
            for (int r = 0; r < 4; ++r)
                out[(size_t)(m0 + wm + mi * 16 + g * 4 + r) * DM + n] = acc[mi][ni][r] + bias;
    }
}

// ---------------- Flash attention, causal. S^T = K@Q^T trick, no LDS. (unchanged) ----------------
__global__ __launch_bounds__(256) void attn_kernel(
    const bf16* __restrict__ Qh, const bf16* __restrict__ Kh, const bf16* __restrict__ Vt,
    bf16* __restrict__ Xo)
{
    int bh = blockIdx.y;
    int lane = threadIdx.x & 63, w = threadIdx.x >> 6;
    int g = lane >> 4, c = lane & 15;
    const bf16* Qb = Qh + (size_t)bh * SEQ * DK;
    const bf16* Kb = Kh + (size_t)bh * SEQ * DK;
    const bf16* Vb = Vt + (size_t)bh * DK * SEQ;
    int q0 = blockIdx.x * 64 + w * 16;

    bf16x8 qf0 = *(const bf16x8*)(Qb + (size_t)(q0 + c) * DK + g * 8);
    bf16x8 qf1 = *(const bf16x8*)(Qb + (size_t)(q0 + c) * DK + 32 + g * 8);

    float m_st = -INFINITY, l_st = 0.f;
    f32x4 o[4] = {};
    int myq = q0 + c;
    int srcA = g * 20;

    int kend = q0 + 16;
    for (int kb = 0; kb < kend; kb += 32) {
        bf16x8 k00 = *(const bf16x8*)(Kb + (size_t)(kb + c) * DK + g * 8);
        bf16x8 k01 = *(const bf16x8*)(Kb + (size_t)(kb + c) * DK + 32 + g * 8);
        bf16x8 k10 = *(const bf16x8*)(Kb + (size_t)(kb + 16 + c) * DK + g * 8);
        bf16x8 k11 = *(const bf16x8*)(Kb + (size_t)(kb + 16 + c) * DK + 32 + g * 8);
        f32x4 st0 = {}, st1 = {};
        st0 = mfma16(k00, qf0, st0); st0 = mfma16(k01, qf1, st0);
        st1 = mfma16(k10, qf0, st1); st1 = mfma16(k11, qf1, st1);
        float s0[4], s1[4];
        float mx = -INFINITY;
#pragma unroll
        for (int r = 0; r < 4; ++r) {
            int key0 = kb + g * 4 + r;
            s0[r] = (key0 <= myq) ? st0[r] * 0.125f : -INFINITY;
            s1[r] = (key0 + 16 <= myq) ? st1[r] * 0.125f : -INFINITY;
            mx = fmaxf(mx, fmaxf(s0[r], s1[r]));
        }
        mx = fmaxf(mx, __shfl_xor(mx, 16, 64));
        mx = fmaxf(mx, __shfl_xor(mx, 32, 64));
        float m_new = fmaxf(m_st, mx);
        float alpha = __expf(m_st - m_new);
        m_st = m_new;
        float psum = 0.f;
#pragma unroll
        for (int r = 0; r < 4; ++r) {
            s0[r] = __expf(s0[r] - m_new);
            s1[r] = __expf(s1[r] - m_new);
            psum += s0[r] + s1[r];
        }
        psum += __shfl_xor(psum, 16, 64);
        psum += __shfl_xor(psum, 32, 64);
        l_st = l_st * alpha + psum;
        float ar[4];
#pragma unroll
        for (int r = 0; r < 4; ++r) ar[r] = __shfl(alpha, srcA + r, 64);
#pragma unroll
        for (int t2 = 0; t2 < 4; ++t2)
#pragma unroll
            for (int r = 0; r < 4; ++r) o[t2][r] *= ar[r];
        bf16x8 pa;
        int use_hi = g >> 1;
        int gsb = (g & 1) * 2;
#pragma unroll
        for (int j = 0; j < 8; ++j) {
            int r = j & 3;
            int srcLane = (gsb + (j >> 2)) * 16 + c;
            float v0 = __shfl(s0[r], srcLane, 64);
            float v1 = __shfl(s1[r], srcLane, 64);
            pa[j] = (bf16)(use_hi ? v1 : v0);
        }
#pragma unroll
        for (int t2 = 0; t2 < 4; ++t2) {
            bf16x8 bv = *(const bf16x8*)(Vb + (size_t)(t2 * 16 + c) * SEQ + kb + g * 8);
            o[t2] = mfma16(pa, bv, o[t2]);
        }
    }
    float inv = 1.f / l_st;
    float ir[4];
#pragma unroll
    for (int r = 0; r < 4; ++r) ir[r] = __shfl(inv, srcA + r, 64);
    int b_ = bh / NH, h = bh % NH;
#pragma unroll
    for (int t2 = 0; t2 < 4; ++t2) {
#pragma unroll
        for (int r = 0; r < 4; ++r) {
            int s = q0 + g * 4 + r;
            Xo[(size_t)(b_ * SEQ + s) * DM + h * DK + t2 * 16 + c] = (bf16)(o[t2][r] * ir[r]);
        }
    }
}

extern "C" void kernel_launch(void* const* d_in, const int* in_sizes, int n_in,
                              void* d_out, int out_size, void* d_ws, size_t ws_size,
                              hipStream_t stream) {
    const float* q  = (const float*)d_in[0];
    const float* k  = (const float*)d_in[1];
    const float* v  = (const float*)d_in[2];
    // d_in[3] = causal tril mask — statically known, unused
    const float* wq = (const float*)d_in[4];
    const float* bq = (const float*)d_in[5];
    const float* wk = (const float*)d_in[6];
    const float* bk = (const float*)d_in[7];
    const float* wv = (const float*)d_in[8];
    const float* bv = (const float*)d_in[9];
    const float* wo = (const float*)d_in[10];
    const float* bo = (const float*)d_in[11];

    bf16* Xb = (bf16*)d_ws;          // 3*XN ; Xb[0] reused as Xo after qkv gemm consumes it
    bf16* Wb = Xb + 3 * (size_t)XN;  // 4*WN
    bf16* Qh = Wb + 4 * (size_t)WN;  // XN
    bf16* Kh = Qh + (size_t)XN;      // XN
    bf16* Vt = Kh + (size_t)XN;      // XN
    bf16* Xo = Xb;                   // alias (safe: Xb fully consumed before attn writes)
    float* out = (float*)d_out;

    dim3 blk(256);
    // total convert elems = 3*XN + 4*WN = 11,796,480 ; /8 per thread /256 per block = 5760
    convert_kernel<<<dim3(5760), blk, 0, stream>>>(q, k, v, wq, wk, wv, wo, Xb, Wb);
    qkv_gemm_kernel<<<dim3(M_ / 128, DM / 64, 3), blk, 0, stream>>>(
        Xb, Wb, bq, bk, bv, Qh, Kh, Vt);
    attn_kernel<<<dim3(SEQ / 64, NB * NH), blk, 0, stream>>>(Qh, Kh, Vt, Xo);
    o_gemm_kernel<<<dim3(M_ / 128, DM / 64), blk, 0, stream>>>(Xo, Wb + 3 * (size_t)WN, bo, out);
}

// Round 4
// 321.341 us; speedup vs baseline: 1.8177x; 1.0036x over previous
//
#include <hip/hip_runtime.h>
#include <hip/hip_bf16.h>

#define DM 768
#define NH 12
#define DK 64
#define SEQ 2048
#define NB 2
#define M_ (NB*SEQ)   // 4096
#define XN 3145728    // M_*DM
#define WN 589824     // DM*DM

typedef __bf16 bf16;
typedef bf16 bf16x2 __attribute__((ext_vector_type(2)));
typedef bf16 bf16x4 __attribute__((ext_vector_type(4)));
typedef bf16 bf16x8 __attribute__((ext_vector_type(8)));
typedef float f32x4 __attribute__((ext_vector_type(4)));

__device__ __forceinline__ f32x4 mfma16(bf16x8 a, bf16x8 b, f32x4 c) {
    return __builtin_amdgcn_mfma_f32_16x16x32_bf16(a, b, c, 0, 0, 0);
}

__device__ __forceinline__ void gload_lds16(const bf16* g, bf16* l) {
    __builtin_amdgcn_global_load_lds(
        (const __attribute__((address_space(1))) void*)g,
        (__attribute__((address_space(3))) void*)l, 16, 0, 0);
}

__device__ __forceinline__ int pack2(float a, float b) {
    bf16x2 t; t[0] = (bf16)a; t[1] = (bf16)b;
    return __builtin_bit_cast(int, t);
}

// ---------------- f32 -> bf16 convert (X: q,k,v ; W: wq,wk,wv,wo) ----------------
__global__ __launch_bounds__(256) void convert_kernel(
    const float* __restrict__ q, const float* __restrict__ k, const float* __restrict__ v,
    const float* __restrict__ wq, const float* __restrict__ wk, const float* __restrict__ wv,
    const float* __restrict__ wo, bf16* __restrict__ Xb, bf16* __restrict__ Wb)
{
    long long e = ((long long)blockIdx.x * 256 + threadIdx.x) * 8;
    const float* src; bf16* dst;
    if (e < 3LL * XN) {
        int z = (int)(e / XN);
        src = (z == 0 ? q : z == 1 ? k : v) + (e - (long long)z * XN);
        dst = Xb + e;
    } else {
        long long e2 = e - 3LL * XN;
        int z = (int)(e2 / WN);
        src = (z == 0 ? wq : z == 1 ? wk : z == 2 ? wv : wo) + (e2 - (long long)z * WN);
        dst = Wb + e2;
    }
    f32x4 a = *(const f32x4*)src;
    f32x4 b = *(const f32x4*)(src + 4);
    bf16x8 o;
#pragma unroll
    for (int j = 0; j < 4; ++j) { o[j] = (bf16)a[j]; o[j + 4] = (bf16)b[j]; }
    *(bf16x8*)dst = o;
}

// ---------------- QKV GEMM: BM=128 BN=64 BK=64, LDS-staged via global_load_lds ----------------
__global__ __launch_bounds__(256) void qkv_gemm_kernel(
    const bf16* __restrict__ Xb, const bf16* __restrict__ Wb,
    const float* __restrict__ bq, const float* __restrict__ bk, const float* __restrict__ bv,
    bf16* __restrict__ Qh, bf16* __restrict__ Kh, bf16* __restrict__ Vt)
{
    __shared__ bf16 lds[12288];
    int z = blockIdx.z;
    const bf16* Ab = Xb + (size_t)z * XN;
    const bf16* Wz = Wb + (size_t)z * WN;
    const float* Bi = (z == 0) ? bq : (z == 1) ? bk : bv;

    int t = threadIdx.x;
    int lane = t & 63, w = t >> 6;
    int g = lane >> 4, c = lane & 15;
    int wm = (w >> 1) * 64, wn = (w & 1) * 32;
    int m0 = blockIdx.x * 128, n0 = blockIdx.y * 64;

    f32x4 acc[4][2] = {};

    const bf16* Agp[4];
#pragma unroll
    for (int r = 0; r < 4; ++r) {
        int e = r * 2048 + t * 8;
        int kk = e >> 12, mm = (e & 4095) >> 5, k8 = e & 31;
        Agp[r] = Ab + (size_t)(m0 + mm) * DM + kk * 32 + k8;
    }
    const bf16* Bgp[2];
#pragma unroll
    for (int r = 0; r < 2; ++r) {
        int e = r * 2048 + t * 8;
        int kk = e >> 11, nn = (e & 2047) >> 5, k8 = e & 31;
        Bgp[r] = Wz + (size_t)(n0 + nn) * DM + kk * 32 + k8;
    }

    for (int kt = 0; kt < 12; ++kt) {
#pragma unroll
        for (int r = 0; r < 4; ++r)
            gload_lds16(Agp[r] + kt * 64, &lds[r * 2048 + t * 8]);
#pragma unroll
        for (int r = 0; r < 2; ++r)
            gload_lds16(Bgp[r] + kt * 64, &lds[8192 + r * 2048 + t * 8]);
        __syncthreads();
        bf16x8 af[4][2], bfr[2][2];
#pragma unroll
        for (int kk = 0; kk < 2; ++kk) {
#pragma unroll
            for (int mi = 0; mi < 4; ++mi)
                af[mi][kk] = *(const bf16x8*)&lds[kk * 4096 + (wm + mi * 16 + c) * 32 + g * 8];
#pragma unroll
            for (int ni = 0; ni < 2; ++ni)
                bfr[ni][kk] = *(const bf16x8*)&lds[8192 + kk * 2048 + (wn + ni * 16 + c) * 32 + g * 8];
        }
#pragma unroll
        for (int mi = 0; mi < 4; ++mi)
#pragma unroll
            for (int ni = 0; ni < 2; ++ni) {
                acc[mi][ni] = mfma16(af[mi][0], bfr[ni][0], acc[mi][ni]);
                acc[mi][ni] = mfma16(af[mi][1], bfr[ni][1], acc[mi][ni]);
            }
        __syncthreads();
    }

    int b_ = m0 >> 11, sbase = m0 & (SEQ - 1);
    int h = blockIdx.y;
    if (z < 2) {
        bf16* dst = (z == 0) ? Qh : Kh;
#pragma unroll
        for (int ni = 0; ni < 2; ++ni) {
            int nl = wn + ni * 16 + c;   // dk
            float bias = Bi[n0 + nl];
#pragma unroll
            for (int mi = 0; mi < 4; ++mi)
#pragma unroll
                for (int r = 0; r < 4; ++r) {
                    int s = sbase + wm + mi * 16 + g * 4 + r;
                    dst[((size_t)(b_ * NH + h) * SEQ + s) * DK + nl] = (bf16)(acc[mi][ni][r] + bias);
                }
        }
    } else {
        // V: transpose 128(s) x 64(dk) tile through LDS -> Vt[bh][dk][s]
#pragma unroll
        for (int ni = 0; ni < 2; ++ni) {
            int nl = wn + ni * 16 + c;
            float bias = Bi[n0 + nl];
#pragma unroll
            for (int mi = 0; mi < 4; ++mi) {
                bf16x4 pk;
#pragma unroll
                for (int r = 0; r < 4; ++r) pk[r] = (bf16)(acc[mi][ni][r] + bias);
                *(bf16x4*)&lds[nl * 136 + wm + mi * 16 + g * 4] = pk;
            }
        }
        __syncthreads();
        int dk = t >> 2, sc = (t & 3) * 32;
        bf16* vdst = Vt + ((size_t)(b_ * NH + h) * DK + dk) * SEQ + sbase + sc;
#pragma unroll
        for (int j = 0; j < 4; ++j)
            *(bf16x8*)(vdst + j * 8) = *(const bf16x8*)&lds[dk * 136 + sc + j * 8];
    }
}

// ---------------- Output projection GEMM: same structure, f32 output ----------------
__global__ __launch_bounds__(256) void o_gemm_kernel(
    const bf16* __restrict__ Xo, const bf16* __restrict__ Wo,
    const float* __restrict__ bo, float* __restrict__ out)
{
    __shared__ bf16 lds[12288];
    int t = threadIdx.x;
    int lane = t & 63, w = t >> 6;
    int g = lane >> 4, c = lane & 15;
    int wm = (w >> 1) * 64, wn = (w & 1) * 32;
    int m0 = blockIdx.x * 128, n0 = blockIdx.y * 64;

    f32x4 acc[4][2] = {};

    const bf16* Agp[4];
#pragma unroll
    for (int r = 0; r < 4; ++r) {
        int e = r * 2048 + t * 8;
        int kk = e >> 12, mm = (e & 4095) >> 5, k8 = e & 31;
        Agp[r] = Xo + (size_t)(m0 + mm) * DM + kk * 32 + k8;
    }
    const bf16* Bgp[2];
#pragma unroll
    for (int r = 0; r < 2; ++r) {
        int e = r * 2048 + t * 8;
        int kk = e >> 11, nn = (e & 2047) >> 5, k8 = e & 31;
        Bgp[r] = Wo + (size_t)(n0 + nn) * DM + kk * 32 + k8;
    }

    for (int kt = 0; kt < 12; ++kt) {
#pragma unroll
        for (int r = 0; r < 4; ++r)
            gload_lds16(Agp[r] + kt * 64, &lds[r * 2048 + t * 8]);
#pragma unroll
        for (int r = 0; r < 2; ++r)
            gload_lds16(Bgp[r] + kt * 64, &lds[8192 + r * 2048 + t * 8]);
        __syncthreads();
        bf16x8 af[4][2], bfr[2][2];
#pragma unroll
        for (int kk = 0; kk < 2; ++kk) {
#pragma unroll
            for (int mi = 0; mi < 4; ++mi)
                af[mi][kk] = *(const bf16x8*)&lds[kk * 4096 + (wm + mi * 16 + c) * 32 + g * 8];
#pragma unroll
            for (int ni = 0; ni < 2; ++ni)
                bfr[ni][kk] = *(const bf16x8*)&lds[8192 + kk * 2048 + (wn + ni * 16 + c) * 32 + g * 8];
        }
#pragma unroll
        for (int mi = 0; mi < 4; ++mi)
#pragma unroll
            for (int ni = 0; ni < 2; ++ni) {
                acc[mi][ni] = mfma16(af[mi][0], bfr[ni][0], acc[mi][ni]);
                acc[mi][ni] = mfma16(af[mi][1], bfr[ni][1], acc[mi][ni]);
            }
        __syncthreads();
    }

#pragma unroll
    for (int ni = 0; ni < 2; ++ni) {
        int n = n0 + wn + ni * 16 + c;
        float bias = bo[n];
#pragma unroll
        for (int mi = 0; mi < 4; ++mi)
#pragma unroll
            for (int r = 0; r < 4; ++r)
                out[(size_t)(m0 + wm + mi * 16 + g * 4 + r) * DM + n] = acc[mi][ni][r] + bias;
    }
}

// ---------------- Flash attention, causal. 64 keys/iter, pipelined K, packed shuffles ----------------
// grid (SEQ/64, NB*NH); block 256 (4 waves). Wave w: q rows [q0, q0+16).
__global__ __launch_bounds__(256) void attn_kernel(
    const bf16* __restrict__ Qh, const bf16* __restrict__ Kh, const bf16* __restrict__ Vt,
    bf16* __restrict__ Xo)
{
    int bh = blockIdx.y;
    int lane = threadIdx.x & 63, w = threadIdx.x >> 6;
    int g = lane >> 4, c = lane & 15;
    const bf16* Qb = Qh + (size_t)bh * SEQ * DK;
    const bf16* Kb = Kh + (size_t)bh * SEQ * DK;
    const bf16* Vb = Vt + (size_t)bh * DK * SEQ;
    int q0 = blockIdx.x * 64 + w * 16;

    // Q as B-operand: lane holds Q[q0+c][dk = 8g..8g+7] (+32 for second half)
    bf16x8 qf0 = *(const bf16x8*)(Qb + (size_t)(q0 + c) * DK + g * 8);
    bf16x8 qf1 = *(const bf16x8*)(Qb + (size_t)(q0 + c) * DK + 32 + g * 8);

    const float SCL = 0.125f * 1.4426950408889634f;  // (1/sqrt(64)) * log2(e)
    float m_st = -INFINITY, l_st = 0.f;
    f32x4 o[4] = {};
    int myq = q0 + c;
    int srcA = g * 20;       // lane holding softmax state of q_local = 4g+r (at +r)
    int kend = q0 + 16;
    int hi = g >> 1;

    bf16x8 kbuf0[8], kbuf1[8];
    auto loadK = [&](int kb, bf16x8* dst) {
#pragma unroll
        for (int i = 0; i < 4; ++i) {
            const bf16* p = Kb + (size_t)(kb + i * 16 + c) * DK + g * 8;
            dst[2 * i]     = *(const bf16x8*)p;
            dst[2 * i + 1] = *(const bf16x8*)(p + 32);
        }
    };
    auto body = [&](int kb, bf16x8* cur, bf16x8* nxt) {
        if (kb + 64 < kend) loadK(kb + 64, nxt);            // prefetch next K
        bf16x8 bv[8];                                       // V for this iter, in flight over softmax
#pragma unroll
        for (int t2 = 0; t2 < 4; ++t2) {
            const bf16* p = Vb + (size_t)(t2 * 16 + c) * SEQ + kb + g * 8;
            bv[2 * t2]     = *(const bf16x8*)p;
            bv[2 * t2 + 1] = *(const bf16x8*)(p + 32);
        }
        // S^T: subtile i holds keys kb+16i..+15; lane(g,c) reg r = S[q=c][key=kb+16i+4g+r]
        float p_[4][4];
        float mx = -INFINITY;
#pragma unroll
        for (int i = 0; i < 4; ++i) {
            f32x4 a = {};
            a = mfma16(cur[2 * i], qf0, a);
            a = mfma16(cur[2 * i + 1], qf1, a);
#pragma unroll
            for (int r = 0; r < 4; ++r) {
                int key = kb + i * 16 + g * 4 + r;
                float vv = (key <= myq) ? a[r] * SCL : -INFINITY;
                p_[i][r] = vv;
                mx = fmaxf(mx, vv);
            }
        }
        mx = fmaxf(mx, __shfl_xor(mx, 16, 64));
        mx = fmaxf(mx, __shfl_xor(mx, 32, 64));
        float m_new = fmaxf(m_st, mx);
        float alpha = exp2f(m_st - m_new);
        m_st = m_new;
        float psum = 0.f;
#pragma unroll
        for (int i = 0; i < 4; ++i)
#pragma unroll
            for (int r = 0; r < 4; ++r) {
                p_[i][r] = exp2f(p_[i][r] - m_new);
                psum += p_[i][r];
            }
        psum += __shfl_xor(psum, 16, 64);
        psum += __shfl_xor(psum, 32, 64);
        l_st = l_st * alpha + psum;
        float ar[4];
#pragma unroll
        for (int r = 0; r < 4; ++r) ar[r] = __shfl(alpha, srcA + r, 64);
#pragma unroll
        for (int t2 = 0; t2 < 4; ++t2)
#pragma unroll
            for (int r = 0; r < 4; ++r) o[t2][r] *= ar[r];
        // pack probabilities of subtile pairs (0,1) and (2,3), shuffle once per pair
        int q01[4], q23[4];
#pragma unroll
        for (int r = 0; r < 4; ++r) {
            q01[r] = pack2(p_[0][r], p_[1][r]);
            q23[r] = pack2(p_[2][r], p_[3][r]);
        }
        // relayout -> A-operand: pa0[j] = P[q=c][key=kb+8g+j], pa1[j] = +32
        bf16x8 pa0, pa1;
#pragma unroll
        for (int j = 0; j < 8; ++j) {
            int src = ((2 * g + (j >> 2)) & 3) * 16 + c;
            int s01 = __shfl(q01[j & 3], src, 64);
            int s23 = __shfl(q23[j & 3], src, 64);
            unsigned short u01 = hi ? (unsigned short)((unsigned)s01 >> 16) : (unsigned short)s01;
            unsigned short u23 = hi ? (unsigned short)((unsigned)s23 >> 16) : (unsigned short)s23;
            pa0[j] = __builtin_bit_cast(bf16, u01);
            pa1[j] = __builtin_bit_cast(bf16, u23);
        }
#pragma unroll
        for (int t2 = 0; t2 < 4; ++t2) {
            o[t2] = mfma16(pa0, bv[2 * t2], o[t2]);
            o[t2] = mfma16(pa1, bv[2 * t2 + 1], o[t2]);
        }
    };

    loadK(0, kbuf0);
    for (int kb = 0; kb < kend; kb += 128) {
        body(kb, kbuf0, kbuf1);
        if (kb + 64 < kend) body(kb + 64, kbuf1, kbuf0);
    }

    float inv = 1.f / l_st;
    float ir[4];
#pragma unroll
    for (int r = 0; r < 4; ++r) ir[r] = __shfl(inv, srcA + r, 64);
    int b_ = bh / NH, h = bh % NH;
#pragma unroll
    for (int t2 = 0; t2 < 4; ++t2)
#pragma unroll
        for (int r = 0; r < 4; ++r) {
            int s = q0 + g * 4 + r;
            Xo[(size_t)(b_ * SEQ + s) * DM + h * DK + t2 * 16 + c] = (bf16)(o[t2][r] * ir[r]);
        }
}

extern "C" void kernel_launch(void* const* d_in, const int* in_sizes, int n_in,
                              void* d_out, int out_size, void* d_ws, size_t ws_size,
                              hipStream_t stream) {
    const float* q  = (const float*)d_in[0];
    const float* k  = (const float*)d_in[1];
    const float* v  = (const float*)d_in[2];
    // d_in[3] = causal tril mask — statically known, unused
    const float* wq = (const float*)d_in[4];
    const float* bq = (const float*)d_in[5];
    const float* wk = (const float*)d_in[6];
    const float* bk = (const float*)d_in[7];
    const float* wv = (const float*)d_in[8];
    const float* bv = (const float*)d_in[9];
    const float* wo = (const float*)d_in[10];
    const float* bo = (const float*)d_in[11];

    bf16* Xb = (bf16*)d_ws;          // 3*XN
    bf16* Wb = Xb + 3 * (size_t)XN;  // 4*WN
    bf16* Qh = Wb + 4 * (size_t)WN;  // XN
    bf16* Kh = Qh + (size_t)XN;      // XN
    bf16* Vt = Kh + (size_t)XN;      // XN
    bf16* Xo = Xb;                   // alias (Xb fully consumed before attn writes)
    float* out = (float*)d_out;

    dim3 blk(256);
    convert_kernel<<<dim3(5760), blk, 0, stream>>>(q, k, v, wq, wk, wv, wo, Xb, Wb);
    qkv_gemm_kernel<<<dim3(M_ / 128, DM / 64, 3), blk, 0, stream>>>(
        Xb, Wb, bq, bk, bv, Qh, Kh, Vt);
    attn_kernel<<<dim3(SEQ / 64, NB * NH), blk, 0, stream>>>(Qh, Kh, Vt, Xo);
    o_gemm_kernel<<<dim3(M_ / 128, DM / 64), blk, 0, stream>>>(Xo, Wb + 3 * (size_t)WN, bo, out);
}

// Round 5
// 244.937 us; speedup vs baseline: 2.3846x; 1.3119x over previous
//
#include <hip/hip_runtime.h>
#include <hip/hip_bf16.h>

#define DM 768
#define NH 12
#define DK 64
#define SEQ 2048
#define NB 2
#define M_ (NB*SEQ)   // 4096
#define XN 3145728    // M_*DM
#define WN 589824     // DM*DM

typedef __bf16 bf16;
typedef bf16 bf16x2 __attribute__((ext_vector_type(2)));
typedef bf16 bf16x4 __attribute__((ext_vector_type(4)));
typedef bf16 bf16x8 __attribute__((ext_vector_type(8)));
typedef float f32x4 __attribute__((ext_vector_type(4)));

__device__ __forceinline__ f32x4 mfma16(bf16x8 a, bf16x8 b, f32x4 c) {
    return __builtin_amdgcn_mfma_f32_16x16x32_bf16(a, b, c, 0, 0, 0);
}

__device__ __forceinline__ void gload_lds16(const bf16* g, bf16* l) {
    __builtin_amdgcn_global_load_lds(
        (const __attribute__((address_space(1))) void*)g,
        (__attribute__((address_space(3))) void*)l, 16, 0, 0);
}

__device__ __forceinline__ int pack2(float a, float b) {
    bf16x2 t; t[0] = (bf16)a; t[1] = (bf16)b;
    return __builtin_bit_cast(int, t);
}

// ---------------- f32 -> bf16 convert (X: q,k,v ; W: wq,wk,wv,wo) ----------------
__global__ __launch_bounds__(256) void convert_kernel(
    const float* __restrict__ q, const float* __restrict__ k, const float* __restrict__ v,
    const float* __restrict__ wq, const float* __restrict__ wk, const float* __restrict__ wv,
    const float* __restrict__ wo, bf16* __restrict__ Xb, bf16* __restrict__ Wb)
{
    long long e = ((long long)blockIdx.x * 256 + threadIdx.x) * 8;
    const float* src; bf16* dst;
    if (e < 3LL * XN) {
        int z = (int)(e / XN);
        src = (z == 0 ? q : z == 1 ? k : v) + (e - (long long)z * XN);
        dst = Xb + e;
    } else {
        long long e2 = e - 3LL * XN;
        int z = (int)(e2 / WN);
        src = (z == 0 ? wq : z == 1 ? wk : z == 2 ? wv : wo) + (e2 - (long long)z * WN);
        dst = Wb + e2;
    }
    f32x4 a = *(const f32x4*)src;
    f32x4 b = *(const f32x4*)(src + 4);
    bf16x8 o;
#pragma unroll
    for (int j = 0; j < 4; ++j) { o[j] = (bf16)a[j]; o[j + 4] = (bf16)b[j]; }
    *(bf16x8*)dst = o;
}

// ---------------- QKV GEMM: BM=128 BN=64 BK=64, LDS-staged via global_load_lds ----------------
__global__ __launch_bounds__(256) void qkv_gemm_kernel(
    const bf16* __restrict__ Xb, const bf16* __restrict__ Wb,
    const float* __restrict__ bq, const float* __restrict__ bk, const float* __restrict__ bv,
    bf16* __restrict__ Qh, bf16* __restrict__ Kh, bf16* __restrict__ Vt)
{
    __shared__ bf16 lds[12288];
    int z = blockIdx.z;
    const bf16* Ab = Xb + (size_t)z * XN;
    const bf16* Wz = Wb + (size_t)z * WN;
    const float* Bi = (z == 0) ? bq : (z == 1) ? bk : bv;

    int t = threadIdx.x;
    int lane = t & 63, w = t >> 6;
    int g = lane >> 4, c = lane & 15;
    int wm = (w >> 1) * 64, wn = (w & 1) * 32;
    int m0 = blockIdx.x * 128, n0 = blockIdx.y * 64;

    f32x4 acc[4][2] = {};

    const bf16* Agp[4];
#pragma unroll
    for (int r = 0; r < 4; ++r) {
        int e = r * 2048 + t * 8;
        int kk = e >> 12, mm = (e & 4095) >> 5, k8 = e & 31;
        Agp[r] = Ab + (size_t)(m0 + mm) * DM + kk * 32 + k8;
    }
    const bf16* Bgp[2];
#pragma unroll
    for (int r = 0; r < 2; ++r) {
        int e = r * 2048 + t * 8;
        int kk = e >> 11, nn = (e & 2047) >> 5, k8 = e & 31;
        Bgp[r] = Wz + (size_t)(n0 + nn) * DM + kk * 32 + k8;
    }

    for (int kt = 0; kt < 12; ++kt) {
#pragma unroll
        for (int r = 0; r < 4; ++r)
            gload_lds16(Agp[r] + kt * 64, &lds[r * 2048 + t * 8]);
#pragma unroll
        for (int r = 0; r < 2; ++r)
            gload_lds16(Bgp[r] + kt * 64, &lds[8192 + r * 2048 + t * 8]);
        __syncthreads();
        bf16x8 af[4][2], bfr[2][2];
#pragma unroll
        for (int kk = 0; kk < 2; ++kk) {
#pragma unroll
            for (int mi = 0; mi < 4; ++mi)
                af[mi][kk] = *(const bf16x8*)&lds[kk * 4096 + (wm + mi * 16 + c) * 32 + g * 8];
#pragma unroll
            for (int ni = 0; ni < 2; ++ni)
                bfr[ni][kk] = *(const bf16x8*)&lds[8192 + kk * 2048 + (wn + ni * 16 + c) * 32 + g * 8];
        }
#pragma unroll
        for (int mi = 0; mi < 4; ++mi)
#pragma unroll
            for (int ni = 0; ni < 2; ++ni) {
                acc[mi][ni] = mfma16(af[mi][0], bfr[ni][0], acc[mi][ni]);
                acc[mi][ni] = mfma16(af[mi][1], bfr[ni][1], acc[mi][ni]);
            }
        __syncthreads();
    }

    int b_ = m0 >> 11, sbase = m0 & (SEQ - 1);
    int h = blockIdx.y;
    if (z < 2) {
        bf16* dst = (z == 0) ? Qh : Kh;
#pragma unroll
        for (int ni = 0; ni < 2; ++ni) {
            int nl = wn + ni * 16 + c;   // dk
            float bias = Bi[n0 + nl];
#pragma unroll
            for (int mi = 0; mi < 4; ++mi)
#pragma unroll
                for (int r = 0; r < 4; ++r) {
                    int s = sbase + wm + mi * 16 + g * 4 + r;
                    dst[((size_t)(b_ * NH + h) * SEQ + s) * DK + nl] = (bf16)(acc[mi][ni][r] + bias);
                }
        }
    } else {
        // V: transpose 128(s) x 64(dk) tile through LDS -> Vt[bh][dk][s]
#pragma unroll
        for (int ni = 0; ni < 2; ++ni) {
            int nl = wn + ni * 16 + c;
            float bias = Bi[n0 + nl];
#pragma unroll
            for (int mi = 0; mi < 4; ++mi) {
                bf16x4 pk;
#pragma unroll
                for (int r = 0; r < 4; ++r) pk[r] = (bf16)(acc[mi][ni][r] + bias);
                *(bf16x4*)&lds[nl * 136 + wm + mi * 16 + g * 4] = pk;
            }
        }
        __syncthreads();
        int dk = t >> 2, sc = (t & 3) * 32;
        bf16* vdst = Vt + ((size_t)(b_ * NH + h) * DK + dk) * SEQ + sbase + sc;
#pragma unroll
        for (int j = 0; j < 4; ++j)
            *(bf16x8*)(vdst + j * 8) = *(const bf16x8*)&lds[dk * 136 + sc + j * 8];
    }
}

// ---------------- Output projection GEMM: same structure, f32 output ----------------
__global__ __launch_bounds__(256) void o_gemm_kernel(
    const bf16* __restrict__ Xo, const bf16* __restrict__ Wo,
    const float* __restrict__ bo, float* __restrict__ out)
{
    __shared__ bf16 lds[12288];
    int t = threadIdx.x;
    int lane = t & 63, w = t >> 6;
    int g = lane >> 4, c = lane & 15;
    int wm = (w >> 1) * 64, wn = (w & 1) * 32;
    int m0 = blockIdx.x * 128, n0 = blockIdx.y * 64;

    f32x4 acc[4][2] = {};

    const bf16* Agp[4];
#pragma unroll
    for (int r = 0; r < 4; ++r) {
        int e = r * 2048 + t * 8;
        int kk = e >> 12, mm = (e & 4095) >> 5, k8 = e & 31;
        Agp[r] = Xo + (size_t)(m0 + mm) * DM + kk * 32 + k8;
    }
    const bf16* Bgp[2];
#pragma unroll
    for (int r = 0; r < 2; ++r) {
        int e = r * 2048 + t * 8;
        int kk = e >> 11, nn = (e & 2047) >> 5, k8 = e & 31;
        Bgp[r] = Wo + (size_t)(n0 + nn) * DM + kk * 32 + k8;
    }

    for (int kt = 0; kt < 12; ++kt) {
#pragma unroll
        for (int r = 0; r < 4; ++r)
            gload_lds16(Agp[r] + kt * 64, &lds[r * 2048 + t * 8]);
#pragma unroll
        for (int r = 0; r < 2; ++r)
            gload_lds16(Bgp[r] + kt * 64, &lds[8192 + r * 2048 + t * 8]);
        __syncthreads();
        bf16x8 af[4][2], bfr[2][2];
#pragma unroll
        for (int kk = 0; kk < 2; ++kk) {
#pragma unroll
            for (int mi = 0; mi < 4; ++mi)
                af[mi][kk] = *(const bf16x8*)&lds[kk * 4096 + (wm + mi * 16 + c) * 32 + g * 8];
#pragma unroll
            for (int ni = 0; ni < 2; ++ni)
                bfr[ni][kk] = *(const bf16x8*)&lds[8192 + kk * 2048 + (wn + ni * 16 + c) * 32 + g * 8];
        }
#pragma unroll
        for (int mi = 0; mi < 4; ++mi)
#pragma unroll
            for (int ni = 0; ni < 2; ++ni) {
                acc[mi][ni] = mfma16(af[mi][0], bfr[ni][0], acc[mi][ni]);
                acc[mi][ni] = mfma16(af[mi][1], bfr[ni][1], acc[mi][ni]);
            }
        __syncthreads();
    }

#pragma unroll
    for (int ni = 0; ni < 2; ++ni) {
        int n = n0 + wn + ni * 16 + c;
        float bias = bo[n];
#pragma unroll
        for (int mi = 0; mi < 4; ++mi)
#pragma unroll
            for (int r = 0; r < 4; ++r)
                out[(size_t)(m0 + wm + mi * 16 + g * 4 + r) * DM + n] = acc[mi][ni][r] + bias;
    }
}

// ---------------- Flash attention, causal. 1 wave/block, mirrored-pair load balancing ----------------
// grid (24*64); block 64. Wave = (bh, p): q-groups q0=16p and q0=2032-16p -> uniform 33 bodies.
__global__ __launch_bounds__(64) void attn_kernel(
    const bf16* __restrict__ Qh, const bf16* __restrict__ Kh, const bf16* __restrict__ Vt,
    bf16* __restrict__ Xo)
{
    int p  = blockIdx.x & 63;
    int bh = blockIdx.x >> 6;
    int lane = threadIdx.x & 63;
    int g = lane >> 4, c = lane & 15;
    const bf16* Qb = Qh + (size_t)bh * SEQ * DK;
    const bf16* Kb = Kh + (size_t)bh * SEQ * DK;
    const bf16* Vb = Vt + (size_t)bh * DK * SEQ;
    int b_ = bh / NH, h = bh % NH;

    const float SCL = 0.125f * 1.4426950408889634f;  // (1/sqrt(64)) * log2(e)
    int srcA = g * 20;       // lane holding softmax state of q_local = 4g+r (at +r)
    int hi = g >> 1;

    bf16x8 kbuf0[8], kbuf1[8];

    auto loadK = [&](int kb, bf16x8* dst) {
#pragma unroll
        for (int i = 0; i < 4; ++i) {
            const bf16* pk = Kb + (size_t)(kb + i * 16 + c) * DK + g * 8;
            dst[2 * i]     = *(const bf16x8*)pk;
            dst[2 * i + 1] = *(const bf16x8*)(pk + 32);
        }
    };

    auto process = [&](int q0) {
        bf16x8 qf0 = *(const bf16x8*)(Qb + (size_t)(q0 + c) * DK + g * 8);
        bf16x8 qf1 = *(const bf16x8*)(Qb + (size_t)(q0 + c) * DK + 32 + g * 8);
        float m_st = -INFINITY, l_st = 0.f;
        f32x4 o[4] = {};
        int myq = q0 + c;
        int kend = q0 + 16;

        auto body = [&](int kb, bf16x8* cur, bf16x8* nxt) {
            if (kb + 64 < kend) loadK(kb + 64, nxt);        // prefetch next K
            bf16x8 bv[8];                                   // V in flight over softmax
#pragma unroll
            for (int t2 = 0; t2 < 4; ++t2) {
                const bf16* pv = Vb + (size_t)(t2 * 16 + c) * SEQ + kb + g * 8;
                bv[2 * t2]     = *(const bf16x8*)pv;
                bv[2 * t2 + 1] = *(const bf16x8*)(pv + 32);
            }
            float p_[4][4];
#pragma unroll
            for (int i = 0; i < 4; ++i) {
                f32x4 a = {};
                a = mfma16(cur[2 * i], qf0, a);
                a = mfma16(cur[2 * i + 1], qf1, a);
#pragma unroll
                for (int r = 0; r < 4; ++r) {
                    int key = kb + i * 16 + g * 4 + r;
                    p_[i][r] = (key <= myq) ? a[r] * SCL : -INFINITY;
                }
            }
            // tree max over 16
            float m0_ = fmaxf(fmaxf(p_[0][0], p_[0][1]), fmaxf(p_[0][2], p_[0][3]));
            float m1_ = fmaxf(fmaxf(p_[1][0], p_[1][1]), fmaxf(p_[1][2], p_[1][3]));
            float m2_ = fmaxf(fmaxf(p_[2][0], p_[2][1]), fmaxf(p_[2][2], p_[2][3]));
            float m3_ = fmaxf(fmaxf(p_[3][0], p_[3][1]), fmaxf(p_[3][2], p_[3][3]));
            float mx = fmaxf(fmaxf(m0_, m1_), fmaxf(m2_, m3_));
            mx = fmaxf(mx, __shfl_xor(mx, 16, 64));
            mx = fmaxf(mx, __shfl_xor(mx, 32, 64));
            float m_new = fmaxf(m_st, mx);
            float alpha = exp2f(m_st - m_new);
            m_st = m_new;
#pragma unroll
            for (int i = 0; i < 4; ++i)
#pragma unroll
                for (int r = 0; r < 4; ++r)
                    p_[i][r] = exp2f(p_[i][r] - m_new);
            // tree sum over 16
            float s0_ = (p_[0][0] + p_[0][1]) + (p_[0][2] + p_[0][3]);
            float s1_ = (p_[1][0] + p_[1][1]) + (p_[1][2] + p_[1][3]);
            float s2_ = (p_[2][0] + p_[2][1]) + (p_[2][2] + p_[2][3]);
            float s3_ = (p_[3][0] + p_[3][1]) + (p_[3][2] + p_[3][3]);
            float psum = (s0_ + s1_) + (s2_ + s3_);
            psum += __shfl_xor(psum, 16, 64);
            psum += __shfl_xor(psum, 32, 64);
            l_st = l_st * alpha + psum;
            float ar[4];
#pragma unroll
            for (int r = 0; r < 4; ++r) ar[r] = __shfl(alpha, srcA + r, 64);
#pragma unroll
            for (int t2 = 0; t2 < 4; ++t2)
#pragma unroll
                for (int r = 0; r < 4; ++r) o[t2][r] *= ar[r];
            int q01[4], q23[4];
#pragma unroll
            for (int r = 0; r < 4; ++r) {
                q01[r] = pack2(p_[0][r], p_[1][r]);
                q23[r] = pack2(p_[2][r], p_[3][r]);
            }
            bf16x8 pa0, pa1;
#pragma unroll
            for (int j = 0; j < 8; ++j) {
                int src = ((2 * g + (j >> 2)) & 3) * 16 + c;
                int s01 = __shfl(q01[j & 3], src, 64);
                int s23 = __shfl(q23[j & 3], src, 64);
                unsigned short u01 = hi ? (unsigned short)((unsigned)s01 >> 16) : (unsigned short)s01;
                unsigned short u23 = hi ? (unsigned short)((unsigned)s23 >> 16) : (unsigned short)s23;
                pa0[j] = __builtin_bit_cast(bf16, u01);
                pa1[j] = __builtin_bit_cast(bf16, u23);
            }
#pragma unroll
            for (int t2 = 0; t2 < 4; ++t2) {
                o[t2] = mfma16(pa0, bv[2 * t2], o[t2]);
                o[t2] = mfma16(pa1, bv[2 * t2 + 1], o[t2]);
            }
        };

        loadK(0, kbuf0);
        for (int kb = 0; kb < kend; kb += 128) {
            body(kb, kbuf0, kbuf1);
            if (kb + 64 < kend) body(kb + 64, kbuf1, kbuf0);
        }

        float inv = 1.f / l_st;
        float ir[4];
#pragma unroll
        for (int r = 0; r < 4; ++r) ir[r] = __shfl(inv, srcA + r, 64);
#pragma unroll
        for (int t2 = 0; t2 < 4; ++t2)
#pragma unroll
            for (int r = 0; r < 4; ++r) {
                int s = q0 + g * 4 + r;
                Xo[(size_t)(b_ * SEQ + s) * DM + h * DK + t2 * 16 + c] = (bf16)(o[t2][r] * ir[r]);
            }
    };

    process(p * 16);           // front group: 1..16 bodies
    process(2032 - p * 16);    // mirror group: 32..17 bodies (total uniform 33)
}

extern "C" void kernel_launch(void* const* d_in, const int* in_sizes, int n_in,
                              void* d_out, int out_size, void* d_ws, size_t ws_size,
                              hipStream_t stream) {
    const float* q  = (const float*)d_in[0];
    const float* k  = (const float*)d_in[1];
    const float* v  = (const float*)d_in[2];
    // d_in[3] = causal tril mask — statically known, unused
    const float* wq = (const float*)d_in[4];
    const float* bq = (const float*)d_in[5];
    const float* wk = (const float*)d_in[6];
    const float* bk = (const float*)d_in[7];
    const float* wv = (const float*)d_in[8];
    const float* bv = (const float*)d_in[9];
    const float* wo = (const float*)d_in[10];
    const float* bo = (const float*)d_in[11];

    bf16* Xb = (bf16*)d_ws;          // 3*XN
    bf16* Wb = Xb + 3 * (size_t)XN;  // 4*WN
    bf16* Qh = Wb + 4 * (size_t)WN;  // XN
    bf16* Kh = Qh + (size_t)XN;      // XN
    bf16* Vt = Kh + (size_t)XN;      // XN
    bf16* Xo = Xb;                   // alias (Xb fully consumed before attn writes)
    float* out = (float*)d_out;

    dim3 blk(256);
    convert_kernel<<<dim3(5760), blk, 0, stream>>>(q, k, v, wq, wk, wv, wo, Xb, Wb);
    qkv_gemm_kernel<<<dim3(M_ / 128, DM / 64, 3), blk, 0, stream>>>(
        Xb, Wb, bq, bk, bv, Qh, Kh, Vt);
    attn_kernel<<<dim3(24 * 64), dim3(64), 0, stream>>>(Qh, Kh, Vt, Xo);
    o_gemm_kernel<<<dim3(M_ / 128, DM / 64), blk, 0, stream>>>(Xo, Wb + 3 * (size_t)WN, bo, out);
}